// Round 9
// baseline (56.986 us; speedup 1.0000x reference)
//
#include <hip/hip_runtime.h>
#include <hip/hip_bf16.h>
#include <stdint.h>

#define HEIGHT 32
#define WIDTH  8192
#define KDIM   256
#define NDIM   512
#define NSLICES 65536                       // B * S = 64 * 1024
#define BM     64                           // slices per block
#define NBLOCKS (NSLICES / BM)              // 1024

typedef float f32x4  __attribute__((ext_vector_type(4)));
typedef float f32x16 __attribute__((ext_vector_type(16)));
typedef short bf16x8 __attribute__((ext_vector_type(8)));

__device__ __forceinline__ ushort f2bf(float x) {
  union { float f; uint32_t u; } un; un.f = x;
  uint32_t u = un.u;
  u += 0x7FFFu + ((u >> 16) & 1u);   // round-to-nearest-even
  return (ushort)(u >> 16);
}

__device__ __forceinline__ void load_row8(float* r, const float* p) {
  f32x4 lo = *reinterpret_cast<const f32x4*>(p);
  f32x4 hi = *reinterpret_cast<const f32x4*>(p + 4);
#pragma unroll
  for (int w = 0; w < 4; ++w) { r[w] = lo[w]; r[4 + w] = hi[w]; }
}

// ---- wt2: B-fragment-tiled layout (proven R7/R8) ----
// wt2[((nb*16 + k0)*64 + lane)*8 + e] = bf16(lin_w[k][n]),
//   n = nb*32 + (lane&31), k = k0*16 + (lane>>5)*8 + e.
__global__ __launch_bounds__(256) void prep_wt2_kernel(const float* __restrict__ lin_w,
                                                       ushort* __restrict__ wt2) {
  const int idx = blockIdx.x * 256 + threadIdx.x;   // 0..16383
  const int ln  = idx & 63;
  const int k0  = (idx >> 6) & 15;
  const int nb  = idx >> 10;
  const int n   = nb * 32 + (ln & 31);
  const int kb  = k0 * 16 + (ln >> 5) * 8;
  bf16x8 p;
#pragma unroll
  for (int e = 0; e < 8; ++e) p[e] = (short)f2bf(lin_w[(size_t)(kb + e) * NDIM + n]);
  *reinterpret_cast<bf16x8*>(wt2 + (size_t)idx * 8) = p;
}

// ---------------- fused: conv -> LDS A-frags -> MFMA -> out ----------------
// Block = 64 slices (2 m-frags). LDS A[mf][(k0*64+ln)*8+e] (32 KB), fragment order.
// GEMM: 4 waves x 2 passes; pass = 2 mf x 2 nf, stores issued per pass so the
// write stream interleaves with B-loads instead of bursting at the end.
__global__ __launch_bounds__(256) void fused_kernel(
    const float* __restrict__ images, const float* __restrict__ conv_w,
    const float* __restrict__ conv_b, const ushort* __restrict__ wt2,
    const float* __restrict__ lin_b, float* __restrict__ out) {
  __shared__ ushort A[2 * 16 * 64 * 8];   // 32 KB

  const int tid = threadIdx.x;
  const int blk = blockIdx.x;             // 0..1023

  float cw[9];
#pragma unroll
  for (int i = 0; i < 9; ++i) cw[i] = conv_w[i];
  const float cb = conv_b[0];

  // ---------- phase 1: conv 64 slices x 32 rows -> A-frags in LDS ----------
  {
    const int sl = tid & 63;          // slice within block
    const int q  = tid >> 6;          // 0..3: rows q*8 .. q*8+7 (rolling window)
    const int s  = blk * 64 + sl;     // global slice
    const int b  = s >> 10;           // batch (1024 slices per batch)
    const int slb = s & 1023;
    const float* base = images + (size_t)b * (HEIGHT * WIDTH) + (size_t)slb * 8;
    const int h0 = q * 8;
    const int mf = sl >> 5;
    const int la = sl & 31;

    float pr[8], cu[8], nx[8];
    if (h0 > 0) load_row8(pr, base + (size_t)(h0 - 1) * WIDTH);
    else {
#pragma unroll
      for (int w = 0; w < 8; ++w) pr[w] = 0.f;
    }
    load_row8(cu, base + (size_t)h0 * WIDTH);

#pragma unroll
    for (int i = 0; i < 8; ++i) {
      const int h = h0 + i;
      if (h + 1 < HEIGHT) load_row8(nx, base + (size_t)(h + 1) * WIDTH);
      else {
#pragma unroll
        for (int w = 0; w < 8; ++w) nx[w] = 0.f;
      }
      float y[8];
#pragma unroll
      for (int w = 0; w < 8; ++w) y[w] = cb;
#pragma unroll
      for (int dw = 0; dw < 3; ++dw) {
        const float c0 = cw[dw], c1 = cw[3 + dw], c2 = cw[6 + dw];
#pragma unroll
        for (int w = 0; w < 8; ++w) {
          const int iw = w + dw - 1;            // per-slice zero padding in w
          if (iw >= 0 && iw < 8) {
            y[w] = fmaf(pr[iw], c0, y[w]);
            y[w] = fmaf(cu[iw], c1, y[w]);
            y[w] = fmaf(nx[iw], c2, y[w]);
          }
        }
      }
      bf16x8 pack;
#pragma unroll
      for (int w = 0; w < 8; ++w) pack[w] = (short)f2bf(fmaxf(y[w], 0.f));
      const int k0 = h >> 1;
      const int ln = ((h & 1) << 5) | la;
      *reinterpret_cast<bf16x8*>(A + (((size_t)mf * 16 + k0) * 64 + ln) * 8) = pack;
#pragma unroll
      for (int w = 0; w < 8; ++w) { pr[w] = cu[w]; cu[w] = nx[w]; }
    }
  }
  __syncthreads();

  // ---------- phase 2: [64 x 256] @ [256 x 512]; 4 waves x 2 passes ----------
  const int lane = tid & 63;
  const int wv   = tid >> 6;
  const int la   = lane & 31;
  const int lb   = lane >> 5;
  const size_t row0 = (size_t)blk * BM;

  const ushort* a0 = A + (size_t)lane * 8;            // mf=0; mf=1 at +16*512
  const ushort* a1 = A + (size_t)(16 * 64 + lane) * 8;

#pragma unroll
  for (int pass = 0; pass < 2; ++pass) {
    const int nfb = wv * 4 + pass * 2;                // first of 2 n-frags
    const ushort* bb = wt2 + ((size_t)nfb * 16) * 512 + (size_t)lane * 8;

    f32x16 acc[2][2];                                 // [mf][nf]
#pragma unroll
    for (int mf = 0; mf < 2; ++mf)
#pragma unroll
      for (int nf = 0; nf < 2; ++nf)
#pragma unroll
        for (int i = 0; i < 16; ++i) acc[mf][nf][i] = 0.f;

#pragma unroll
    for (int k0 = 0; k0 < 16; ++k0) {
      const bf16x8 af0 = *reinterpret_cast<const bf16x8*>(a0 + (size_t)k0 * 512);
      const bf16x8 af1 = *reinterpret_cast<const bf16x8*>(a1 + (size_t)k0 * 512);
      const bf16x8 bf0 = *reinterpret_cast<const bf16x8*>(bb + (size_t)k0 * 512);
      const bf16x8 bf1 = *reinterpret_cast<const bf16x8*>(bb + (size_t)(16 + k0) * 512);
      acc[0][0] = __builtin_amdgcn_mfma_f32_32x32x16_bf16(af0, bf0, acc[0][0], 0, 0, 0);
      acc[1][0] = __builtin_amdgcn_mfma_f32_32x32x16_bf16(af1, bf0, acc[1][0], 0, 0, 0);
      acc[0][1] = __builtin_amdgcn_mfma_f32_32x32x16_bf16(af0, bf1, acc[0][1], 0, 0, 0);
      acc[1][1] = __builtin_amdgcn_mfma_f32_32x32x16_bf16(af1, bf1, acc[1][1], 0, 0, 0);
    }

    // store this pass's 64x64 block now (interleaves write stream with B-loads)
#pragma unroll
    for (int mf = 0; mf < 2; ++mf) {
#pragma unroll
      for (int nf = 0; nf < 2; ++nf) {
        const int col = (nfb + nf) * 32 + la;
        const float bias = lin_b[col];
#pragma unroll
        for (int reg = 0; reg < 16; ++reg) {
          const int rr = mf * 32 + (reg & 3) + 8 * (reg >> 2) + 4 * lb;
          out[(row0 + rr) * NDIM + col] = acc[mf][nf][reg] + bias;
        }
      }
    }
  }
}

extern "C" void kernel_launch(void* const* d_in, const int* in_sizes, int n_in,
                              void* d_out, int out_size, void* d_ws, size_t ws_size,
                              hipStream_t stream) {
  const float* images = (const float*)d_in[0];
  const float* conv_w = (const float*)d_in[1];
  const float* conv_b = (const float*)d_in[2];
  const float* lin_w  = (const float*)d_in[3];
  const float* lin_b  = (const float*)d_in[4];
  float* out = (float*)d_out;
  ushort* wt2 = (ushort*)d_ws;      // 256 KB

  hipLaunchKernelGGL(prep_wt2_kernel, dim3(64), dim3(256), 0, stream, lin_w, wt2);
  hipLaunchKernelGGL(fused_kernel, dim3(NBLOCKS), dim3(256), 0, stream,
                     images, conv_w, conv_b, wt2, lin_b, out);
}